// Round 7
// baseline (439.535 us; speedup 1.0000x reference)
//
#include <hip/hip_runtime.h>

// Round 7: ONE fused barrier-free GEMM kernel.
// 16 nodes/block = 64 virtual rows (classes s,x,y,z x 16 nodes), 512 threads,
// 8 waves; wave = 16 output cols x all 4 row-tiles.  B (both combined weight
// matrices) lives in registers (loaded once per block from L2); A lives in LDS
// in the HW-validated de-interleaved form.  K-loop has ZERO barriers
// (3 barriers/block total vs 40 in round 6).

#define MUL 128
#define DIM 512
#define KTOT 640
#define NSTEPS 20
#define NODES 16
#define INV_LIN 0.08838834764831845f   // 1/sqrt(128)
#define INV_TP  0.04419417382415922f   // 1/sqrt(512)

typedef float f32x4 __attribute__((ext_vector_type(4)));
typedef __bf16 bf16x8 __attribute__((ext_vector_type(8)));

__device__ inline unsigned short f2bf(float x) {
    unsigned u = __float_as_uint(x);
    u += 0x7fffu + ((u >> 16) & 1u);
    return (unsigned short)(u >> 16);
}

// ---------------------------------------------------------------------------
// Prep: combined transposed weights Bt[w][k] bf16, scales folded (validated).
// ---------------------------------------------------------------------------
__global__ __launch_bounds__(256) void prep_weights(
        const float* __restrict__ Wl0, const float* __restrict__ Wl1,
        const float* __restrict__ Wt0, const float* __restrict__ Wt1,
        unsigned short* __restrict__ Bt0, unsigned short* __restrict__ Bt1) {
    int idx = blockIdx.x * 256 + threadIdx.x;
    if (idx >= 2 * MUL * KTOT) return;
    int mat = idx / (MUL * KTOT);
    int r   = idx % (MUL * KTOT);
    int w = r / KTOT, k = r % KTOT;
    const float* Wl = mat ? Wl1 : Wl0;
    const float* Wt = mat ? Wt1 : Wt0;
    float val;
    if (k < MUL) {
        val = Wl[k * MUL + w] * INV_LIN;
    } else {
        int kk = k - MUL;
        val = Wt[(kk >> 2) * 512 + (kk & 3) * 128 + w] * INV_TP;
    }
    (mat ? Bt1 : Bt0)[w * KTOT + k] = f2bf(val);
}

// ---------------------------------------------------------------------------
// Fused kernel: whole output row for 16 nodes per block.
// Row-tiles: rt=0 -> s (uses Bt0), rt=1..3 -> xyz components (use Bt1).
// A-fragment row = lane&15 = node-in-tile; k-slot = (lane>>4)*8+i  (validated).
// B-fragment   : lane(lr,g) holds Bt[w = wc*16+lr][ks*32 + g*8 + i] (validated
//                Blds semantics, now register-resident).
// D            : col(w) = lane&15, row(node) = (lane>>4)*4 + r   (validated).
// ---------------------------------------------------------------------------
#define POOL_BYTES 34816   // Mde+Fde 2*4*16*136*2 = 34816 ; Ost 32768 reuses it
__global__ __launch_bounds__(512, 2) void k_fused(
        const float* __restrict__ m_i, const float* __restrict__ nf,
        const float* __restrict__ attrs,
        const unsigned short* __restrict__ Bt0,
        const unsigned short* __restrict__ Bt1,
        float* __restrict__ out, int N) {
    __shared__ __align__(16) char pool[POOL_BYTES];
    __bf16 (*Mde)[NODES][136] = (__bf16(*)[NODES][136])(pool);           // [4][16][136]
    __bf16 (*Fde)[NODES][136] = (__bf16(*)[NODES][136])(pool + 17408);

    int tid = threadIdx.x;
    int wc = tid >> 6, l = tid & 63;      // wc = col-tile (16 cols)
    int lr = l & 15, g = l >> 4;

    long nodeBase = (long)blockIdx.x * NODES;

    // ---- B fragments into registers (one-time, overlaps A staging) ----
    int w = wc * 16 + lr;
    bf16x8 b0[NSTEPS], b1[NSTEPS];
    #pragma unroll
    for (int ks = 0; ks < NSTEPS; ++ks) {
        b0[ks] = *(const bf16x8*)&Bt0[w * KTOT + ks * 32 + g * 8];
        b1[ks] = *(const bf16x8*)&Bt1[w * KTOT + ks * 32 + g * 8];
    }

    // ---- stage A de-interleaved: class 0 = cols 0..127 ; class 1+c = col
    //      128 + u*3 + c  ->  Mde/Fde[class][node][u]   (validated pattern) ----
    for (int c = tid; c < NODES * 128; c += 512) {
        int nl = c >> 7, q = c & 127;
        long node = nodeBase + nl; if (node >= N) node = N - 1;
        f32x4 x = *(const f32x4*)&m_i[node * DIM + q * 4];
        f32x4 y = *(const f32x4*)&nf [node * DIM + q * 4];
        #pragma unroll
        for (int j = 0; j < 4; ++j) {
            int col = q * 4 + j;
            int cls, u;
            if (col < 128) { cls = 0; u = col; }
            else { int cc = col - 128; cls = 1 + cc % 3; u = cc / 3; }
            Mde[cls][nl][u] = (__bf16)x[j];
            Fde[cls][nl][u] = (__bf16)y[j];
        }
    }

    long nodeA = nodeBase + lr; if (nodeA >= N) nodeA = N - 1;
    f32x4 at = *(const f32x4*)&attrs[nodeA * 4];

    f32x4 acc[4] = {};
    __syncthreads();

    // ---- K-loop: NO barriers.  B from regs, A from LDS. ----
    #pragma unroll
    for (int ks = 0; ks < NSTEPS; ++ks) {
        bf16x8 af[4];
        if (ks < 4) {                       // lin: k = u
            #pragma unroll
            for (int rt = 0; rt < 4; ++rt)
                af[rt] = *(const bf16x8*)&Mde[rt][lr][ks * 32 + g * 8];
        } else {                            // tp: k = 128+u*4+v = f[u]*attr[v]
            int u0 = (ks - 4) * 8 + g * 2;
            #pragma unroll
            for (int rt = 0; rt < 4; ++rt) {
                float fx = (float)Fde[rt][lr][u0];
                float fy = (float)Fde[rt][lr][u0 + 1];
                bf16x8 a;
                a[0]=(__bf16)(fx*at[0]); a[1]=(__bf16)(fx*at[1]);
                a[2]=(__bf16)(fx*at[2]); a[3]=(__bf16)(fx*at[3]);
                a[4]=(__bf16)(fy*at[0]); a[5]=(__bf16)(fy*at[1]);
                a[6]=(__bf16)(fy*at[2]); a[7]=(__bf16)(fy*at[3]);
                af[rt] = a;
            }
        }
        acc[0] = __builtin_amdgcn_mfma_f32_16x16x32_bf16(af[0], b0[ks], acc[0], 0, 0, 0);
        acc[1] = __builtin_amdgcn_mfma_f32_16x16x32_bf16(af[1], b1[ks], acc[1], 0, 0, 0);
        acc[2] = __builtin_amdgcn_mfma_f32_16x16x32_bf16(af[2], b1[ks], acc[2], 0, 0, 0);
        acc[3] = __builtin_amdgcn_mfma_f32_16x16x32_bf16(af[3], b1[ks], acc[3], 0, 0, 0);
    }

    // ---- epilogue: acc -> Ost (fp32, reuse pool) -> coalesced dump ----
    __syncthreads();                       // all K-loop LDS reads done
    float (*Ost)[DIM] = (float(*)[DIM])pool;     // [16][512]
    #pragma unroll
    for (int r = 0; r < 4; ++r) {
        int nl = g * 4 + r;
        int wv_ = wc * 16 + lr;
        Ost[nl][wv_]                = acc[0][r];             // s  : col = w
        Ost[nl][128 + wv_ * 3 + 0]  = acc[1][r];             // x  : col = 128+w*3+m
        Ost[nl][128 + wv_ * 3 + 1]  = acc[2][r];
        Ost[nl][128 + wv_ * 3 + 2]  = acc[3][r];
    }
    __syncthreads();
    for (int c = tid; c < NODES * 128; c += 512) {
        int nl = c >> 7, q = c & 127;
        long node = nodeBase + nl;
        if (node < N)
            *(f32x4*)&out[node * DIM + q * 4] = *(const f32x4*)&Ost[nl][q * 4];
    }
}

extern "C" void kernel_launch(void* const* d_in, const int* in_sizes, int n_in,
                              void* d_out, int out_size, void* d_ws, size_t ws_size,
                              hipStream_t stream) {
    const float* m_i  = (const float*)d_in[0];
    const float* nf   = (const float*)d_in[1];
    const float* attr = (const float*)d_in[2];
    const float* Wl0  = (const float*)d_in[3];
    const float* Wl1  = (const float*)d_in[4];
    const float* Wt0  = (const float*)d_in[5];
    const float* Wt1  = (const float*)d_in[6];
    float* out = (float*)d_out;
    int N = in_sizes[0] / DIM;

    unsigned short* Bt0 = (unsigned short*)d_ws;
    unsigned short* Bt1 = Bt0 + MUL * KTOT;

    int prep_total = 2 * MUL * KTOT;
    hipLaunchKernelGGL(prep_weights, dim3((prep_total + 255) / 256), dim3(256), 0, stream,
                       Wl0, Wl1, Wt0, Wt1, Bt0, Bt1);
    hipLaunchKernelGGL(k_fused, dim3((N + NODES - 1) / NODES), dim3(512), 0, stream,
                       m_i, nf, attr, Bt0, Bt1, out, N);
}

// Round 8
// 283.471 us; speedup vs baseline: 1.5505x; 1.5505x over previous
//
#include <hip/hip_runtime.h>

// Round 8: fused barrier-free kernel, B streamed from L2 in-loop.
// r7's B-in-registers spilled (VGPR=104 < 160 needed; FETCH/WRITE +100MB of
// scratch traffic).  Fix: prep packs B fragment-major so each (col-tile,kstep)
// fragment is a contiguous 1KB wave-load; K-loop loads it on demand (2 loads
// per kstep, zero barriers).  32 nodes/block halves per-node B-load count.

#define MUL 128
#define DIM 512
#define KTOT 640
#define NSTEPS 20
#define NODES 32          // nodes per block (2 node-tiles of 16)
#define INV_LIN 0.08838834764831845f   // 1/sqrt(128)
#define INV_TP  0.04419417382415922f   // 1/sqrt(512)

typedef float f32x4 __attribute__((ext_vector_type(4)));
typedef __bf16 bf16x8 __attribute__((ext_vector_type(8)));

__device__ inline unsigned short f2bf(float x) {
    unsigned u = __float_as_uint(x);
    u += 0x7fffu + ((u >> 16) & 1u);
    return (unsigned short)(u >> 16);
}

// ---------------------------------------------------------------------------
// Prep: combined weights, packed FRAGMENT-MAJOR for the wave loads:
//   P[((ct*20 + ks)*4 + g)*16 + lr][i]  (bf16x8 elements, lane l = g*16+lr)
// value at (w,k): w = ct*16+lr, k = ks*32 + g*8 + i  (validated mapping).
// ---------------------------------------------------------------------------
__global__ __launch_bounds__(256) void prep_weights(
        const float* __restrict__ Wl0, const float* __restrict__ Wl1,
        const float* __restrict__ Wt0, const float* __restrict__ Wt1,
        unsigned short* __restrict__ P0, unsigned short* __restrict__ P1) {
    int idx = blockIdx.x * 256 + threadIdx.x;
    if (idx >= 2 * MUL * KTOT) return;
    int mat = idx / (MUL * KTOT);
    int r   = idx % (MUL * KTOT);
    int w = r / KTOT, k = r % KTOT;
    const float* Wl = mat ? Wl1 : Wl0;
    const float* Wt = mat ? Wt1 : Wt0;
    float val;
    if (k < MUL) {
        val = Wl[k * MUL + w] * INV_LIN;
    } else {
        int kk = k - MUL;
        val = Wt[(kk >> 2) * 512 + (kk & 3) * 128 + w] * INV_TP;
    }
    int ct = w >> 4, lr = w & 15;
    int ks = k >> 5, kr = k & 31, g = kr >> 3, i = kr & 7;
    (mat ? P1 : P0)[((((ct * NSTEPS + ks) * 4 + g) * 16 + lr) << 3) + i] = f2bf(val);
}

// ---------------------------------------------------------------------------
// Fused kernel: 32 nodes/block, 512 threads, 8 waves; wave = col-tile ct.
// Wave computes 4 classes (s,x,y,z) x 2 node-tiles = 8 MFMA tiles, K=640.
// A in LDS de-interleaved (validated); B fragments streamed from L2 in-loop.
// Zero barriers in the K-loop.
// ---------------------------------------------------------------------------
#define POOL_BYTES 69632   // Mde+Fde 2*4*32*136*2 = 69632 ; Ost 65536 reuses it
__global__ __launch_bounds__(512, 2) void k_fused(
        const float* __restrict__ m_i, const float* __restrict__ nf,
        const float* __restrict__ attrs,
        const bf16x8* __restrict__ P0, const bf16x8* __restrict__ P1,
        float* __restrict__ out, int N) {
    __shared__ __align__(16) char pool[POOL_BYTES];
    __bf16 (*Mde)[NODES][136] = (__bf16(*)[NODES][136])(pool);           // [4][32][136]
    __bf16 (*Fde)[NODES][136] = (__bf16(*)[NODES][136])(pool + 34816);

    int tid = threadIdx.x;
    int ct = tid >> 6, l = tid & 63;      // ct = col-tile (16 cols)
    int lr = l & 15, g = l >> 4;

    long nodeBase = (long)blockIdx.x * NODES;

    // ---- stage A de-interleaved (validated pattern): class 0 = cols 0..127;
    //      class 1+c = col 128 + u*3 + c  ->  Mde/Fde[class][node][u] ----
    for (int c = tid; c < NODES * 128; c += 512) {
        int nl = c >> 7, q = c & 127;
        long node = nodeBase + nl; if (node >= N) node = N - 1;
        f32x4 x = *(const f32x4*)&m_i[node * DIM + q * 4];
        f32x4 y = *(const f32x4*)&nf [node * DIM + q * 4];
        #pragma unroll
        for (int j = 0; j < 4; ++j) {
            int col = q * 4 + j;
            int cls, u;
            if (col < 128) { cls = 0; u = col; }
            else { int cc = col - 128; cls = 1 + cc % 3; u = cc / 3; }
            Mde[cls][nl][u] = (__bf16)x[j];
            Fde[cls][nl][u] = (__bf16)y[j];
        }
    }

    long nA0 = nodeBase + lr;      if (nA0 >= N) nA0 = N - 1;
    long nA1 = nodeBase + 16 + lr; if (nA1 >= N) nA1 = N - 1;
    f32x4 at0 = *(const f32x4*)&attrs[nA0 * 4];
    f32x4 at1 = *(const f32x4*)&attrs[nA1 * 4];

    f32x4 acc[4][2] = {};
    __syncthreads();

    // ---- K-loop: ZERO barriers.  B streamed (1KB coalesced load per frag). ----
    #pragma unroll
    for (int ks = 0; ks < 4; ++ks) {           // lin: k = u
        bf16x8 b0 = P0[(ct * NSTEPS + ks) * 64 + l];
        bf16x8 b1 = P1[(ct * NSTEPS + ks) * 64 + l];
        #pragma unroll
        for (int nt = 0; nt < 2; ++nt) {
            int nl = nt * 16 + lr;
            #pragma unroll
            for (int cls = 0; cls < 4; ++cls) {
                bf16x8 af = *(const bf16x8*)&Mde[cls][nl][ks * 32 + g * 8];
                acc[cls][nt] = __builtin_amdgcn_mfma_f32_16x16x32_bf16(
                    af, cls ? b1 : b0, acc[cls][nt], 0, 0, 0);
            }
        }
    }
    #pragma unroll 2
    for (int ks = 4; ks < NSTEPS; ++ks) {      // tp: k = 128+u*4+v = f[u]*attr[v]
        bf16x8 b0 = P0[(ct * NSTEPS + ks) * 64 + l];
        bf16x8 b1 = P1[(ct * NSTEPS + ks) * 64 + l];
        int u0 = (ks - 4) * 8 + g * 2;
        #pragma unroll
        for (int nt = 0; nt < 2; ++nt) {
            int nl = nt * 16 + lr;
            f32x4 at = nt ? at1 : at0;
            #pragma unroll
            for (int cls = 0; cls < 4; ++cls) {
                float fx = (float)Fde[cls][nl][u0];
                float fy = (float)Fde[cls][nl][u0 + 1];
                bf16x8 a;
                a[0]=(__bf16)(fx*at[0]); a[1]=(__bf16)(fx*at[1]);
                a[2]=(__bf16)(fx*at[2]); a[3]=(__bf16)(fx*at[3]);
                a[4]=(__bf16)(fy*at[0]); a[5]=(__bf16)(fy*at[1]);
                a[6]=(__bf16)(fy*at[2]); a[7]=(__bf16)(fy*at[3]);
                acc[cls][nt] = __builtin_amdgcn_mfma_f32_16x16x32_bf16(
                    a, cls ? b1 : b0, acc[cls][nt], 0, 0, 0);
            }
        }
    }

    // ---- epilogue (validated r7 formulas, extended by nt) ----
    __syncthreads();                       // all K-loop LDS reads done
    float (*Ost)[DIM] = (float(*)[DIM])pool;     // [32][512]
    int wv_ = ct * 16 + lr;
    #pragma unroll
    for (int nt = 0; nt < 2; ++nt)
        #pragma unroll
        for (int r = 0; r < 4; ++r) {
            int nl = nt * 16 + g * 4 + r;
            Ost[nl][wv_]               = acc[0][nt][r];   // s  : col = w
            Ost[nl][128 + wv_ * 3 + 0] = acc[1][nt][r];   // xyz: col = 128+w*3+m
            Ost[nl][128 + wv_ * 3 + 1] = acc[2][nt][r];
            Ost[nl][128 + wv_ * 3 + 2] = acc[3][nt][r];
        }
    __syncthreads();
    for (int c = tid; c < NODES * 128; c += 512) {
        int nl = c >> 7, q = c & 127;
        long node = nodeBase + nl;
        if (node < N)
            *(f32x4*)&out[node * DIM + q * 4] = *(const f32x4*)&Ost[nl][q * 4];
    }
}

extern "C" void kernel_launch(void* const* d_in, const int* in_sizes, int n_in,
                              void* d_out, int out_size, void* d_ws, size_t ws_size,
                              hipStream_t stream) {
    const float* m_i  = (const float*)d_in[0];
    const float* nf   = (const float*)d_in[1];
    const float* attr = (const float*)d_in[2];
    const float* Wl0  = (const float*)d_in[3];
    const float* Wl1  = (const float*)d_in[4];
    const float* Wt0  = (const float*)d_in[5];
    const float* Wt1  = (const float*)d_in[6];
    float* out = (float*)d_out;
    int N = in_sizes[0] / DIM;

    unsigned short* P0 = (unsigned short*)d_ws;     // 160KB packed fragments
    unsigned short* P1 = P0 + MUL * KTOT;           // 160KB

    int prep_total = 2 * MUL * KTOT;
    hipLaunchKernelGGL(prep_weights, dim3((prep_total + 255) / 256), dim3(256), 0, stream,
                       Wl0, Wl1, Wt0, Wt1, P0, P1);
    hipLaunchKernelGGL(k_fused, dim3((N + NODES - 1) / NODES), dim3(512), 0, stream,
                       m_i, nf, attr, (const bf16x8*)P0, (const bf16x8*)P1, out, N);
}

// Round 9
// 198.685 us; speedup vs baseline: 2.2122x; 1.4267x over previous
//
#include <hip/hip_runtime.h>

// Round 9: register-blocked fused kernel.
// r8 counters: VALUBusy 41% / MfmaUtil 8.4% -> the tp af-build was done
// redundantly by all 8 waves (build depends on node, not col-tile).
// Fix: waves own 32 cols (2 sub-tiles) so each build feeds 2 MFMAs (4x -> 2x
// less redundant per MFMA), and blocks shrink to 16 nodes (LDS 35KB -> 4
// blocks/CU, ~16 waves/CU for latency hiding).  Zero barriers in K-loop.

#define MUL 128
#define DIM 512
#define KTOT 640
#define NSTEPS 20
#define NODES 16
#define INV_LIN 0.08838834764831845f   // 1/sqrt(128)
#define INV_TP  0.04419417382415922f   // 1/sqrt(512)

typedef float f32x4 __attribute__((ext_vector_type(4)));
typedef __bf16 bf16x8 __attribute__((ext_vector_type(8)));

__device__ inline unsigned short f2bf(float x) {
    unsigned u = __float_as_uint(x);
    u += 0x7fffu + ((u >> 16) & 1u);
    return (unsigned short)(u >> 16);
}

// ---------------------------------------------------------------------------
// Prep: combined weights, packed fragment-major, ct2-contiguous:
//   element (w,k): ct=w>>5, ct2=(w>>4)&1, lr=w&15; ks=k>>5, g=(k>>3)&3, i=k&7
//   P[(((ct*20+ks)*2+ct2)*64 + g*16+lr)*8 + i]
// so a wave's per-kstep B for its 32 cols is 2KB contiguous.
// Value mapping validated (r2 values, r3/r8 fragment semantics).
// ---------------------------------------------------------------------------
__global__ __launch_bounds__(256) void prep_weights(
        const float* __restrict__ Wl0, const float* __restrict__ Wl1,
        const float* __restrict__ Wt0, const float* __restrict__ Wt1,
        unsigned short* __restrict__ P0, unsigned short* __restrict__ P1) {
    int idx = blockIdx.x * 256 + threadIdx.x;
    if (idx >= 2 * MUL * KTOT) return;
    int mat = idx / (MUL * KTOT);
    int r   = idx % (MUL * KTOT);
    int w = r / KTOT, k = r % KTOT;
    const float* Wl = mat ? Wl1 : Wl0;
    const float* Wt = mat ? Wt1 : Wt0;
    float val;
    if (k < MUL) {
        val = Wl[k * MUL + w] * INV_LIN;
    } else {
        int kk = k - MUL;
        val = Wt[(kk >> 2) * 512 + (kk & 3) * 128 + w] * INV_TP;
    }
    int ct = w >> 5, ct2 = (w >> 4) & 1, lr = w & 15;
    int ks = k >> 5, g = (k >> 3) & 3, i = k & 7;
    (mat ? P1 : P0)[((((ct * NSTEPS + ks) * 2 + ct2) * 64 + g * 16 + lr) << 3) + i] = f2bf(val);
}

// ---------------------------------------------------------------------------
// Fused kernel: 16 nodes/block, 256 threads, 4 waves; wave ct owns cols
// ct*32 .. ct*32+31 (2 sub-tiles), x 4 classes x 16 nodes.
// A in LDS de-interleaved (validated); B streamed from L2 (2KB/matrix/kstep).
// ---------------------------------------------------------------------------
#define POOL_BYTES 34816   // Mde+Fde 2*4*16*136*2 = 34816 ; Ost 32768 reuses it
__global__ __launch_bounds__(256, 4) void k_fused(
        const float* __restrict__ m_i, const float* __restrict__ nf,
        const float* __restrict__ attrs,
        const bf16x8* __restrict__ P0, const bf16x8* __restrict__ P1,
        float* __restrict__ out, int N) {
    __shared__ __align__(16) char pool[POOL_BYTES];
    __bf16 (*Mde)[NODES][136] = (__bf16(*)[NODES][136])(pool);          // [4][16][136]
    __bf16 (*Fde)[NODES][136] = (__bf16(*)[NODES][136])(pool + 17408);

    int tid = threadIdx.x;
    int ct = tid >> 6, l = tid & 63;      // ct = 32-col group
    int lr = l & 15, g = l >> 4;

    long nodeBase = (long)blockIdx.x * NODES;

    // ---- stage A de-interleaved (validated): class 0 = cols 0..127;
    //      class 1+c = col 128 + u*3 + c  ->  Mde/Fde[class][node][u] ----
    for (int c = tid; c < NODES * 128; c += 256) {
        int nl = c >> 7, q = c & 127;
        long node = nodeBase + nl; if (node >= N) node = N - 1;
        f32x4 x = *(const f32x4*)&m_i[node * DIM + q * 4];
        f32x4 y = *(const f32x4*)&nf [node * DIM + q * 4];
        #pragma unroll
        for (int j = 0; j < 4; ++j) {
            int col = q * 4 + j;
            int cls, u;
            if (col < 128) { cls = 0; u = col; }
            else { int cc = col - 128; cls = 1 + cc % 3; u = cc / 3; }
            Mde[cls][nl][u] = (__bf16)x[j];
            Fde[cls][nl][u] = (__bf16)y[j];
        }
    }

    long nA = nodeBase + lr; if (nA >= N) nA = N - 1;
    f32x4 at = *(const f32x4*)&attrs[nA * 4];

    f32x4 acc[4][2] = {};
    __syncthreads();

    // ---- K-loop: ZERO barriers.  B streamed; af feeds 2 sub-tiles. ----
    #pragma unroll
    for (int ks = 0; ks < 4; ++ks) {           // lin: k = u
        bf16x8 b0[2], b1[2];
        #pragma unroll
        for (int c2 = 0; c2 < 2; ++c2) {
            b0[c2] = P0[((ct * NSTEPS + ks) * 2 + c2) * 64 + l];
            b1[c2] = P1[((ct * NSTEPS + ks) * 2 + c2) * 64 + l];
        }
        #pragma unroll
        for (int cls = 0; cls < 4; ++cls) {
            bf16x8 af = *(const bf16x8*)&Mde[cls][lr][ks * 32 + g * 8];
            #pragma unroll
            for (int c2 = 0; c2 < 2; ++c2)
                acc[cls][c2] = __builtin_amdgcn_mfma_f32_16x16x32_bf16(
                    af, cls ? b1[c2] : b0[c2], acc[cls][c2], 0, 0, 0);
        }
    }
    #pragma unroll 2
    for (int ks = 4; ks < NSTEPS; ++ks) {      // tp: k = 128+u*4+v = f[u]*attr[v]
        bf16x8 b0[2], b1[2];
        #pragma unroll
        for (int c2 = 0; c2 < 2; ++c2) {
            b0[c2] = P0[((ct * NSTEPS + ks) * 2 + c2) * 64 + l];
            b1[c2] = P1[((ct * NSTEPS + ks) * 2 + c2) * 64 + l];
        }
        int u0 = (ks - 4) * 8 + g * 2;
        #pragma unroll
        for (int cls = 0; cls < 4; ++cls) {
            float fx = (float)Fde[cls][lr][u0];
            float fy = (float)Fde[cls][lr][u0 + 1];
            bf16x8 a;
            a[0]=(__bf16)(fx*at[0]); a[1]=(__bf16)(fx*at[1]);
            a[2]=(__bf16)(fx*at[2]); a[3]=(__bf16)(fx*at[3]);
            a[4]=(__bf16)(fy*at[0]); a[5]=(__bf16)(fy*at[1]);
            a[6]=(__bf16)(fy*at[2]); a[7]=(__bf16)(fy*at[3]);
            #pragma unroll
            for (int c2 = 0; c2 < 2; ++c2)
                acc[cls][c2] = __builtin_amdgcn_mfma_f32_16x16x32_bf16(
                    a, cls ? b1[c2] : b0[c2], acc[cls][c2], 0, 0, 0);
        }
    }

    // ---- epilogue (validated r7 formulas; col = ct*32 + c2*16 + lr) ----
    __syncthreads();                       // all K-loop LDS reads done
    float (*Ost)[DIM] = (float(*)[DIM])pool;     // [16][512]
    #pragma unroll
    for (int c2 = 0; c2 < 2; ++c2) {
        int wv_ = ct * 32 + c2 * 16 + lr;
        #pragma unroll
        for (int r = 0; r < 4; ++r) {
            int nl = g * 4 + r;
            Ost[nl][wv_]               = acc[0][c2][r];   // s  : col = w
            Ost[nl][128 + wv_ * 3 + 0] = acc[1][c2][r];   // xyz: col = 128+w*3+m
            Ost[nl][128 + wv_ * 3 + 1] = acc[2][c2][r];
            Ost[nl][128 + wv_ * 3 + 2] = acc[3][c2][r];
        }
    }
    __syncthreads();
    for (int c = tid; c < NODES * 128; c += 256) {
        int nl = c >> 7, q = c & 127;
        long node = nodeBase + nl;
        if (node < N)
            *(f32x4*)&out[node * DIM + q * 4] = *(const f32x4*)&Ost[nl][q * 4];
    }
}

extern "C" void kernel_launch(void* const* d_in, const int* in_sizes, int n_in,
                              void* d_out, int out_size, void* d_ws, size_t ws_size,
                              hipStream_t stream) {
    const float* m_i  = (const float*)d_in[0];
    const float* nf   = (const float*)d_in[1];
    const float* attr = (const float*)d_in[2];
    const float* Wl0  = (const float*)d_in[3];
    const float* Wl1  = (const float*)d_in[4];
    const float* Wt0  = (const float*)d_in[5];
    const float* Wt1  = (const float*)d_in[6];
    float* out = (float*)d_out;
    int N = in_sizes[0] / DIM;

    unsigned short* P0 = (unsigned short*)d_ws;     // 160KB packed fragments
    unsigned short* P1 = P0 + MUL * KTOT;           // 160KB

    int prep_total = 2 * MUL * KTOT;
    hipLaunchKernelGGL(prep_weights, dim3((prep_total + 255) / 256), dim3(256), 0, stream,
                       Wl0, Wl1, Wt0, Wt1, P0, P1);
    hipLaunchKernelGGL(k_fused, dim3((N + NODES - 1) / NODES), dim3(256), 0, stream,
                       m_i, nf, attr, (const bf16x8*)P0, (const bf16x8*)P1, out, N);
}